// Round 1
// 854.325 us; speedup vs baseline: 1.1974x; 1.1974x over previous
//
#include <hip/hip_runtime.h>
#include <hip/hip_bf16.h>

// Self-attention (SAGAN-style) B=4, C=512, N=4096 (64x64), D=64.
// FLOAT32 in/out (per the reference's dtypes).
// out0 = gamma * (V @ A^T) + x   [B,C,64,64]  f32
// out1 = A = softmax(Q K)        [B,N,N]      f32
// Pipeline:
//   prep_weights: WqT/WkT [C][D] f32 (uniform s_load rows), Wvb bf16
//   transpose_cast: x f32 [C][N] -> xTb bf16 [N][C]   (for V MFMA B-operand)
//   proj_qk: f32 VALU, Q[n][d] & K[d][n]  (f32 keeps logits accurate)
//   proj_v:  bf16 MFMA, V[c][n] bf16 ws
//   attn_softmax: f32 energy+softmax; writes f32 A to d_out + bf16 copy to ws
//   pv_out_fast: m97-style LDS-staged 128x128 bf16 MFMA GEMM + residual epi.
//     (round 2: replaced latency-bound per-fragment global loads — MfmaUtil
//      was 8.2%, HBM 7.3%, occupancy 23% -> pure latency-bound. Stage V/A
//      tiles via global_load_lds width=16, 2-barrier loop, 4-wave reuse.)

#define B_ 4
#define C_ 512
#define D_ 64
#define N_ 4096

typedef __hip_bfloat16 bf16;
typedef __attribute__((ext_vector_type(8))) short bf16x8;   // 8 bf16 = 4 VGPRs
typedef __attribute__((ext_vector_type(4))) float f32x4;

// async global->LDS, 16 bytes per lane. lds ptr must be wave-uniform base;
// HW writes base + lane*16. Global src is per-lane.
__device__ __forceinline__ void gload16(const void* g, void* l) {
    __builtin_amdgcn_global_load_lds(
        (__attribute__((address_space(1))) void*)g,
        (__attribute__((address_space(3))) void*)l, 16, 0, 0);
}

// ------------------------------------------------------------ weight prep
__global__ __launch_bounds__(256) void prep_weights(
        const float* __restrict__ Wq, const float* __restrict__ Wk,
        const float* __restrict__ Wv,
        float* __restrict__ WqT, float* __restrict__ WkT,
        bf16* __restrict__ Wvb) {
    int i = blockIdx.x * 256 + threadIdx.x;
    if (i < 32768) {                 // WqT[c][d] = Wq[d][c]
        int d = i >> 9, c = i & 511;
        WqT[c * 64 + d] = Wq[i];
    } else if (i < 65536) {
        int j = i - 32768;
        int d = j >> 9, c = j & 511;
        WkT[c * 64 + d] = Wk[j];
    } else {
        int j = i - 65536;
        if (j < 262144) Wvb[j] = __float2bfloat16(Wv[j]);
    }
}

// ------------------------------------------------------- transpose + cast
__global__ __launch_bounds__(256) void transpose_cast(const float* __restrict__ x,
                                                      bf16* __restrict__ xT) {
    __shared__ bf16 tile[32][33];
    int b = blockIdx.z;
    int n0 = blockIdx.x * 32;
    int c0 = blockIdx.y * 32;
    int tx = threadIdx.x;   // 0..31
    int ty = threadIdx.y;   // 0..7
    const float* xb = x + (size_t)b * C_ * N_;
    bf16* xTb = xT + (size_t)b * N_ * C_;
#pragma unroll
    for (int k = 0; k < 32; k += 8)
        tile[ty + k][tx] = __float2bfloat16(xb[(size_t)(c0 + ty + k) * N_ + n0 + tx]);
    __syncthreads();
#pragma unroll
    for (int k = 0; k < 32; k += 8)
        xTb[(size_t)(n0 + ty + k) * C_ + c0 + tx] = tile[tx][ty + k];
}

// ------------------------------------------------------ Q/K f32 projection
// blockIdx.z: 0 -> Q[b][n][d], 1 -> K[b][d][n]. One thread per token.
__global__ __launch_bounds__(256) void proj_qk(
        const float* __restrict__ x,
        const float* __restrict__ WqT, const float* __restrict__ WkT,
        const float* __restrict__ bq, const float* __restrict__ bk,
        float* __restrict__ Q, float* __restrict__ Km) {
    int b = blockIdx.y;
    int which = blockIdx.z;
    int n = blockIdx.x * 256 + threadIdx.x;
    const float* WT = which ? WkT : WqT;
    const float* bias = which ? bk : bq;
    const float* xb = x + (size_t)b * C_ * N_;

    float acc[64];
#pragma unroll
    for (int d = 0; d < 64; d++) acc[d] = 0.f;

    for (int c = 0; c < 512; c++) {
        float xv = xb[(size_t)c * N_ + n];
        const float* wrow = WT + c * 64;   // uniform -> scalar loads
#pragma unroll
        for (int d = 0; d < 64; d += 4) {
            float4 w = *(const float4*)(wrow + d);
            acc[d + 0] += w.x * xv;
            acc[d + 1] += w.y * xv;
            acc[d + 2] += w.z * xv;
            acc[d + 3] += w.w * xv;
        }
    }

    if (which == 0) {
        float* q = Q + ((size_t)b * N_ + n) * 64;
#pragma unroll
        for (int d = 0; d < 64; d += 4) {
            float4 v;
            v.x = acc[d + 0] + bias[d + 0];
            v.y = acc[d + 1] + bias[d + 1];
            v.z = acc[d + 2] + bias[d + 2];
            v.w = acc[d + 3] + bias[d + 3];
            *(float4*)(q + d) = v;
        }
    } else {
        float* kb = Km + (size_t)b * 64 * N_;
#pragma unroll
        for (int d = 0; d < 64; d++)
            kb[(size_t)d * N_ + n] = acc[d] + bias[d];
    }
}

// --------------------------------------------------------- V bf16 MFMA GEMM
// V[c][n] = sum_k Wvb[c][k] * xTb[n][k] + bv[c]. One wave, 64x64 tile.
__global__ __launch_bounds__(64) void proj_v(
        const bf16* __restrict__ Wvb, const bf16* __restrict__ xTb,
        const float* __restrict__ bv, bf16* __restrict__ V) {
    int b = blockIdx.z;
    int r0 = blockIdx.y * 64;      // cout
    int c0 = blockIdx.x * 64;      // n
    int lane = threadIdx.x;
    int l15 = lane & 15;
    int kq  = lane >> 4;
    const bf16* Bb = xTb + (size_t)b * N_ * C_;

    f32x4 acc[4][4];
#pragma unroll
    for (int i = 0; i < 4; i++)
#pragma unroll
        for (int j = 0; j < 4; j++)
#pragma unroll
            for (int r = 0; r < 4; r++) acc[i][j][r] = 0.f;

    for (int k = 0; k < 512; k += 32) {
        bf16x8 af[4], bfr[4];
#pragma unroll
        for (int i = 0; i < 4; i++)
            af[i] = *(const bf16x8*)(Wvb + (size_t)(r0 + i * 16 + l15) * 512 + k + kq * 8);
#pragma unroll
        for (int j = 0; j < 4; j++)
            bfr[j] = *(const bf16x8*)(Bb + (size_t)(c0 + j * 16 + l15) * 512 + k + kq * 8);
#pragma unroll
        for (int i = 0; i < 4; i++)
#pragma unroll
            for (int j = 0; j < 4; j++)
                acc[i][j] = __builtin_amdgcn_mfma_f32_16x16x32_bf16(af[i], bfr[j], acc[i][j], 0, 0, 0);
    }

    bf16* Vb = V + (size_t)b * C_ * N_;
#pragma unroll
    for (int i = 0; i < 4; i++)
#pragma unroll
        for (int j = 0; j < 4; j++)
#pragma unroll
            for (int r = 0; r < 4; r++) {
                int row = r0 + i * 16 + kq * 4 + r;   // C/D: row=(lane>>4)*4+reg
                int col = c0 + j * 16 + l15;          //      col=lane&15
                Vb[(size_t)row * N_ + col] = __float2bfloat16(acc[i][j][r] + bv[row]);
            }
}

// ------------------------------------------------- energy + fused softmax
// 8 rows per block (256 threads). f32 throughout; writes f32 A (+ bf16 copy).
__global__ __launch_bounds__(256, 2) void attn_softmax(
        const float* __restrict__ Q, const float* __restrict__ Km,
        float* __restrict__ attF, bf16* __restrict__ attB) {
    int b = blockIdx.y;
    int n0 = blockIdx.x * 8;
    int tid = threadIdx.x;

    __shared__ float Qs[64][8];   // [d][r]
    __shared__ float red[8][4];

    for (int t = tid; t < 512; t += 256) {
        int r = t >> 6, d = t & 63;
        Qs[d][r] = Q[(size_t)b * N_ * 64 + (size_t)(n0 + r) * 64 + d];
    }
    __syncthreads();

    float acc[8][16];
#pragma unroll
    for (int r = 0; r < 8; r++)
#pragma unroll
        for (int ch = 0; ch < 16; ch++) acc[r][ch] = 0.f;

    const float* Kb = Km + (size_t)b * 64 * N_;
    for (int d = 0; d < 64; d++) {
        float qv[8];
#pragma unroll
        for (int r = 0; r < 8; r++) qv[r] = Qs[d][r];
#pragma unroll
        for (int ch = 0; ch < 16; ch++) {
            float kv = Kb[(size_t)d * N_ + ch * 256 + tid];
#pragma unroll
            for (int r = 0; r < 8; r++) acc[r][ch] = fmaf(kv, qv[r], acc[r][ch]);
        }
    }

    float mx[8];
#pragma unroll
    for (int r = 0; r < 8; r++) {
        float m = acc[r][0];
#pragma unroll
        for (int ch = 1; ch < 16; ch++) m = fmaxf(m, acc[r][ch]);
        for (int off = 32; off; off >>= 1) m = fmaxf(m, __shfl_down(m, off, 64));
        if ((tid & 63) == 0) red[r][tid >> 6] = m;
    }
    __syncthreads();
#pragma unroll
    for (int r = 0; r < 8; r++)
        mx[r] = fmaxf(fmaxf(red[r][0], red[r][1]), fmaxf(red[r][2], red[r][3]));
    __syncthreads();

    float inv[8];
#pragma unroll
    for (int r = 0; r < 8; r++) {
        float s = 0.f;
#pragma unroll
        for (int ch = 0; ch < 16; ch++) {
            acc[r][ch] = __expf(acc[r][ch] - mx[r]);
            s += acc[r][ch];
        }
        for (int off = 32; off; off >>= 1) s += __shfl_down(s, off, 64);
        if ((tid & 63) == 0) red[r][tid >> 6] = s;
    }
    __syncthreads();
#pragma unroll
    for (int r = 0; r < 8; r++)
        inv[r] = 1.f / (red[r][0] + red[r][1] + red[r][2] + red[r][3]);

    float* af = attF + (size_t)b * N_ * N_;
    bf16* ab = attB ? attB + (size_t)b * N_ * N_ : (bf16*)0;
#pragma unroll
    for (int r = 0; r < 8; r++)
#pragma unroll
        for (int ch = 0; ch < 16; ch++) {
            float p = acc[r][ch] * inv[r];
            size_t idx = (size_t)(n0 + r) * N_ + ch * 256 + tid;
            af[idx] = p;
            if (ab) ab[idx] = __float2bfloat16(p);
        }
}

// --------------------------------------------- PV GEMM + residual epilogue
// O[c][m] = sum_n V[c][n] * A[m][n];  out = gamma*O + x (f32).
// m97 structure: 128x128 tile, BK=32, 4 waves (2c x 2m, 64x64 each),
// global_load_lds width=16 staging, single-buffer 2-barrier K-loop.
__global__ __launch_bounds__(256, 2) void pv_out_fast(
        const bf16* __restrict__ V, const bf16* __restrict__ attB,
        const float* __restrict__ x, const float* __restrict__ gamma,
        float* __restrict__ out) {
    int b = blockIdx.z;
    int c0 = blockIdx.y * 128;     // output rows (channels)
    int m0 = blockIdx.x * 128;     // output cols (tokens)
    int tid = threadIdx.x;
    int wv = tid >> 6;             // wave 0..3
    int lane = tid & 63;
    int l15 = lane & 15;
    int kq  = lane >> 4;
    int wr = wv >> 1;              // wave c-half (0/1)
    int wc = wv & 1;               // wave m-half (0/1)

    __shared__ bf16 Vs[128 * 32];  // [row c][k] linear, 8 KB
    __shared__ bf16 As[128 * 32];  // [row m][k] linear, 8 KB

    const bf16* Vb = V + (size_t)b * C_ * N_;
    const bf16* Ab = attB + (size_t)b * N_ * N_;

    // staging map: thread t loads 16B; elem e = rnd*2048 + t*8; row=e>>5 col=e&31
    int srow = tid >> 2;           // 0..63 (+64 in round 1)
    int scol = (tid & 3) * 8;
    // wave-uniform LDS bases (elements): rnd*2048 + wv*512
    bf16* VsW0 = Vs + wv * 512;
    bf16* AsW0 = As + wv * 512;

    f32x4 acc[4][4];
#pragma unroll
    for (int i = 0; i < 4; i++)
#pragma unroll
        for (int j = 0; j < 4; j++)
#pragma unroll
            for (int r = 0; r < 4; r++) acc[i][j][r] = 0.f;

    for (int kt = 0; kt < N_; kt += 32) {
        // ---- stage 128x32 V-tile and A-tile (4 async 16B loads/thread)
#pragma unroll
        for (int rnd = 0; rnd < 2; rnd++) {
            int row = srow + rnd * 64;
            gload16(Vb + (size_t)(c0 + row) * N_ + kt + scol, VsW0 + rnd * 2048);
            gload16(Ab + (size_t)(m0 + row) * N_ + kt + scol, AsW0 + rnd * 2048);
        }
        __syncthreads();   // drains vmcnt -> tiles visible

        // ---- compute: 8 ds_read_b128 + 16 MFMA per wave
        bf16x8 af[4], bfr[4];
#pragma unroll
        for (int i = 0; i < 4; i++)
            af[i] = *(const bf16x8*)(Vs + (wr * 64 + i * 16 + l15) * 32 + kq * 8);
#pragma unroll
        for (int j = 0; j < 4; j++)
            bfr[j] = *(const bf16x8*)(As + (wc * 64 + j * 16 + l15) * 32 + kq * 8);
#pragma unroll
        for (int i = 0; i < 4; i++)
#pragma unroll
            for (int j = 0; j < 4; j++)
                acc[i][j] = __builtin_amdgcn_mfma_f32_16x16x32_bf16(af[i], bfr[j], acc[i][j], 0, 0, 0);
        __syncthreads();   // all waves done reading before restage
    }

    float g = gamma[0];
    const float* xb = x + (size_t)b * C_ * N_;
    float* ob = out + (size_t)b * C_ * N_;
#pragma unroll
    for (int i = 0; i < 4; i++)
#pragma unroll
        for (int j = 0; j < 4; j++)
#pragma unroll
            for (int r = 0; r < 4; r++) {
                int row = c0 + wr * 64 + i * 16 + kq * 4 + r;
                int col = m0 + wc * 64 + j * 16 + l15;
                size_t idx = (size_t)row * N_ + col;
                ob[idx] = g * acc[i][j][r] + xb[idx];
            }
}

// -------------------- fallback PV (f32 attention, no bf16 ws copy avail)
__global__ __launch_bounds__(256, 2) void pv_out(
        const bf16* __restrict__ V, const bf16* __restrict__ attB,
        const float* __restrict__ attF,
        const float* __restrict__ x, const float* __restrict__ gamma,
        float* __restrict__ out) {
    int b = blockIdx.z;
    int wave = threadIdx.x >> 6;
    int c0 = blockIdx.y * 128 + (wave >> 1) * 64;
    int m0 = blockIdx.x * 128 + (wave & 1) * 64;
    int lane = threadIdx.x & 63;
    int l15 = lane & 15;
    int kq  = lane >> 4;

    const bf16* Vb = V + (size_t)b * C_ * N_;
    const bf16* AbB = attB ? attB + (size_t)b * N_ * N_ : (const bf16*)0;
    const float* AbF = attF + (size_t)b * N_ * N_;

    f32x4 acc[4][4];
#pragma unroll
    for (int i = 0; i < 4; i++)
#pragma unroll
        for (int j = 0; j < 4; j++)
#pragma unroll
            for (int r = 0; r < 4; r++) acc[i][j][r] = 0.f;

    for (int n = 0; n < N_; n += 32) {
        bf16x8 af[4], bfr[4];
#pragma unroll
        for (int i = 0; i < 4; i++)
            af[i] = *(const bf16x8*)(Vb + (size_t)(c0 + i * 16 + l15) * N_ + n + kq * 8);
        if (AbB) {
#pragma unroll
            for (int j = 0; j < 4; j++)
                bfr[j] = *(const bf16x8*)(AbB + (size_t)(m0 + j * 16 + l15) * N_ + n + kq * 8);
        } else {
#pragma unroll
            for (int j = 0; j < 4; j++) {
                const float* ap = AbF + (size_t)(m0 + j * 16 + l15) * N_ + n + kq * 8;
                float4 u = *(const float4*)ap;
                float4 w = *(const float4*)(ap + 4);
                bf16x8 bb;
                bf16* pb = (bf16*)&bb;
                pb[0] = __float2bfloat16(u.x); pb[1] = __float2bfloat16(u.y);
                pb[2] = __float2bfloat16(u.z); pb[3] = __float2bfloat16(u.w);
                pb[4] = __float2bfloat16(w.x); pb[5] = __float2bfloat16(w.y);
                pb[6] = __float2bfloat16(w.z); pb[7] = __float2bfloat16(w.w);
                bfr[j] = bb;
            }
        }
#pragma unroll
        for (int i = 0; i < 4; i++)
#pragma unroll
            for (int j = 0; j < 4; j++)
                acc[i][j] = __builtin_amdgcn_mfma_f32_16x16x32_bf16(af[i], bfr[j], acc[i][j], 0, 0, 0);
    }

    float g = gamma[0];
    const float* xb = x + (size_t)b * C_ * N_;
    float* ob = out + (size_t)b * C_ * N_;
#pragma unroll
    for (int i = 0; i < 4; i++)
#pragma unroll
        for (int j = 0; j < 4; j++)
#pragma unroll
            for (int r = 0; r < 4; r++) {
                int row = c0 + i * 16 + kq * 4 + r;
                int col = m0 + j * 16 + l15;
                size_t idx = (size_t)row * N_ + col;
                ob[idx] = g * acc[i][j][r] + xb[idx];
            }
}

// ------------------------------------------------------------------ launch
extern "C" void kernel_launch(void* const* d_in, const int* in_sizes, int n_in,
                              void* d_out, int out_size, void* d_ws, size_t ws_size,
                              hipStream_t stream) {
    const float* x     = (const float*)d_in[0];
    const float* Wq    = (const float*)d_in[1];
    const float* bq    = (const float*)d_in[2];
    const float* Wk    = (const float*)d_in[3];
    const float* bk    = (const float*)d_in[4];
    const float* Wv    = (const float*)d_in[5];
    const float* bv    = (const float*)d_in[6];
    const float* gamma = (const float*)d_in[7];
    (void)in_sizes; (void)n_in; (void)out_size;

    float* out  = (float*)d_out;
    float* attF = out + (size_t)B_ * C_ * N_;   // second tuple element, f32

    char* ws = (char*)d_ws;
    // layout (bytes): all offsets 16B-aligned
    float* Q   = (float*)(ws + 0);                      //  4 MB [B][N][D]
    float* K   = (float*)(ws + 4194304);                //  4 MB [B][D][N]
    bf16*  V   = (bf16*) (ws + 8388608);                // 16 MB [B][C][N]
    bf16*  xTb = (bf16*) (ws + 25165824);               // 16 MB [B][N][C]
    float* WqT = (float*)(ws + 41943040);               // 128 KB [C][D]
    float* WkT = (float*)(ws + 42074112);               // 128 KB [C][D]
    bf16*  Wvb = (bf16*) (ws + 42205184);               // 512 KB [C][C]
    bf16*  attB = (bf16*)(ws + 42729472);               // 128 MB [B][N][N]
    const size_t full_need = 42729472ULL + (size_t)B_ * N_ * N_ * 2;
    bf16* attB_use = (ws_size >= full_need) ? attB : (bf16*)0;

    prep_weights<<<1280, 256, 0, stream>>>(Wq, Wk, Wv, WqT, WkT, Wvb);

    transpose_cast<<<dim3(N_ / 32, C_ / 32, B_), dim3(32, 8), 0, stream>>>(x, xTb);

    proj_qk<<<dim3(N_ / 256, B_, 2), 256, 0, stream>>>(x, WqT, WkT, bq, bk, Q, K);

    proj_v<<<dim3(N_ / 64, C_ / 64, B_), 64, 0, stream>>>(Wvb, xTb, bv, V);

    attn_softmax<<<dim3(N_ / 8, B_), 256, 0, stream>>>(Q, K, attF, attB_use);

    if (attB_use) {
        pv_out_fast<<<dim3(N_ / 128, C_ / 128, B_), 256, 0, stream>>>(
            V, attB_use, x, gamma, out);
    } else {
        pv_out<<<dim3(N_ / 128, C_ / 128, B_), 256, 0, stream>>>(
            V, attB_use, attF, x, gamma, out);
    }
}